// Round 1
// baseline (12334.184 us; speedup 1.0000x reference)
//
#include <hip/hip_runtime.h>
#include <hip/hip_bf16.h>
#include <math.h>

// LSTM: S=512, B=32, I=1024, H=1024, L=2
// d_in: x[512][32][1024] f32, h0[2][32][1024] f32, c0[2][32][1024] f32,
//       W[2][2048][4096] f32 (rows 0-1023 input part, 1024-2047 hidden part;
//       cols = [f|g|i|o] gates), b[2][4096] f32
// d_out: outs[512][32][1024] f32, h_fin[2][32][1024] f32, c_fin[2][32][1024] f32

typedef short bf16x8 __attribute__((ext_vector_type(8)));
typedef float f32x4 __attribute__((ext_vector_type(4)));
typedef unsigned short u16x8 __attribute__((ext_vector_type(8)));

union ABFrag { bf16x8 v; uint2 u[2]; unsigned short s[8]; };

__device__ __forceinline__ unsigned short f2bf(float x){
  unsigned u = __float_as_uint(x);
  u = u + 0x7FFFu + ((u >> 16) & 1u);   // round-to-nearest-even
  return (unsigned short)(u >> 16);
}
__device__ __forceinline__ float sigf(float x){ return 1.0f / (1.0f + __expf(-x)); }

// ---- convert x (f32) -> bf16, same [512][32][1024] layout, 8 elems/thread ----
__global__ void k_conv_x(const float* __restrict__ x, u16x8* __restrict__ xb){
  int i = blockIdx.x * blockDim.x + threadIdx.x;   // 2,097,152 threads
  const float4* xf = (const float4*)x;
  float4 a = xf[i * 2];
  float4 c = xf[i * 2 + 1];
  u16x8 o = { f2bf(a.x), f2bf(a.y), f2bf(a.z), f2bf(a.w),
              f2bf(c.x), f2bf(c.y), f2bf(c.z), f2bf(c.w) };
  xb[i] = o;
}

// ---- pack W (f32) -> bf16 MFMA B-fragments ----
// wpack[layer][nt(256)][kt(64)][lane(64)] : 8 bf16 = lane's B frag for that k-tile.
// Same (lane-block, elem)->k map as the A-side loads:
//   k = kt*32 + 4*(lane>>4) + (i&3) + 16*(i>>2),  col = nt*16 + (lane&15)
__global__ void k_pack_w(const float* __restrict__ W, u16x8* __restrict__ wpack){
  int t = blockIdx.x * blockDim.x + threadIdx.x;   // 2,097,152 threads
  int lane  = t & 63;
  int kt    = (t >> 6) & 63;
  int nt    = (t >> 12) & 255;
  int layer = t >> 20;
  int col = nt * 16 + (lane & 15);
  int kb  = kt * 32 + (lane >> 4) * 4;
  const float* Wl = W + (size_t)layer * 2048 * 4096;
  u16x8 o;
  #pragma unroll
  for(int i = 0; i < 8; ++i){
    int k = kb + (i & 3) + ((i >> 2) << 4);
    o[i] = f2bf(Wl[(size_t)k * 4096 + col]);
  }
  wpack[t] = o;
}

// ---- init states from h0/c0 ----
__global__ void k_init(const float* __restrict__ h0, const float* __restrict__ c0,
                       unsigned short* __restrict__ h1x, unsigned short* __restrict__ h2bf,
                       float* __restrict__ c_state, float* __restrict__ h_state){
  int j = blockIdx.x * blockDim.x + threadIdx.x;   // 65,536 threads
  float hv = h0[j], cv = c0[j];
  c_state[j] = cv;
  h_state[j] = hv;
  int layer = j >> 15, rc = j & 32767;
  if(layer == 0) h1x[rc]          = f2bf(hv);  // h1 history slot t=-1
  else           h2bf[32768 + rc] = f2bf(hv);  // h2 double-buffer slot 1 (read at p=1)
}

// ---- one pipelined step: blocks 0-63 = layer1 step p, blocks 64-127 = layer2 step p-1
// Each block (128 thr = 2 waves) owns 16 hidden cols; wave w does rows 16w..16w+15,
// all 4 gates (no cross-wave exchange needed: C/D layouts of the 4 gate tiles align).
__global__ __launch_bounds__(128) void lstm_step(
    const unsigned short* __restrict__ xbf,
    const bf16x8* __restrict__ wpk,
    const float* __restrict__ bias,
    unsigned short* __restrict__ h1x,
    unsigned short* __restrict__ h2bf,
    float* __restrict__ c_state,
    float* __restrict__ h_state,
    float* __restrict__ outs,
    int p)
{
  const int bid = blockIdx.x;
  const int layer = bid >> 6;
  const int g = bid & 63;
  const unsigned short *src1, *src2;
  unsigned short* hdst;
  int t;
  if(layer == 0){
    if(p >= 512) return;
    t = p;
    src1 = xbf + (size_t)p * 32768;            // x[t]
    src2 = h1x + (size_t)p * 32768;            // h1(t-1)
    hdst = h1x + (size_t)(p + 1) * 32768;      // h1(t)
  } else {
    if(p < 1) return;
    t = p - 1;
    src1 = h1x + (size_t)p * 32768;            // h1seq[t] (written last launch)
    src2 = h2bf + (size_t)(p & 1) * 32768;     // h2(t-1)
    hdst = h2bf + (size_t)((p & 1) ^ 1) * 32768;
  }
  const int tid = threadIdx.x;
  const int w  = tid >> 6;
  const int l  = tid & 63;
  const int lm = l & 15;
  const int lk = l >> 4;
  const int col = g * 16 + lm;                 // hidden column

  // bias folded into accumulator init (all 4 C/D regs share col = lane&15)
  const float* bl = bias + layer * 4096;
  const float bF = bl[col], bG = bl[1024 + col], bI = bl[2048 + col], bO = bl[3072 + col];
  f32x4 aF = {bF, bF, bF, bF};
  f32x4 aG = {bG, bG, bG, bG};
  f32x4 aI = {bI, bI, bI, bI};
  f32x4 aO = {bO, bO, bO, bO};

  const size_t wq0 = ((size_t)(layer * 256 +   0 + g)) * 4096 + l;
  const size_t wq1 = ((size_t)(layer * 256 +  64 + g)) * 4096 + l;
  const size_t wq2 = ((size_t)(layer * 256 + 128 + g)) * 4096 + l;
  const size_t wq3 = ((size_t)(layer * 256 + 192 + g)) * 4096 + l;

  const int arow = (w * 16 + lm) * 1024 + lk * 4;
  const unsigned short* s1 = src1 + arow;
  const unsigned short* s2 = src2 + arow;

#define KSTEP(SRC, KT, KOFF) { \
    ABFrag a; \
    a.u[0] = *reinterpret_cast<const uint2*>((SRC) + (KOFF)); \
    a.u[1] = *reinterpret_cast<const uint2*>((SRC) + (KOFF) + 16); \
    bf16x8 b0 = wpk[wq0 + (size_t)(KT) * 64]; \
    bf16x8 b1 = wpk[wq1 + (size_t)(KT) * 64]; \
    bf16x8 b2 = wpk[wq2 + (size_t)(KT) * 64]; \
    bf16x8 b3 = wpk[wq3 + (size_t)(KT) * 64]; \
    aF = __builtin_amdgcn_mfma_f32_16x16x32_bf16(a.v, b0, aF, 0, 0, 0); \
    aG = __builtin_amdgcn_mfma_f32_16x16x32_bf16(a.v, b1, aG, 0, 0, 0); \
    aI = __builtin_amdgcn_mfma_f32_16x16x32_bf16(a.v, b2, aI, 0, 0, 0); \
    aO = __builtin_amdgcn_mfma_f32_16x16x32_bf16(a.v, b3, aO, 0, 0, 0); \
  }

  #pragma unroll 8
  for(int kt = 0; kt < 32; ++kt) KSTEP(s1, kt, kt * 32)
  #pragma unroll 8
  for(int kt = 32; kt < 64; ++kt) KSTEP(s2, kt, (kt - 32) * 32)
#undef KSTEP

  float* cs = c_state + (size_t)layer * 32768;
  float* hs = h_state + (size_t)layer * 32768;
  #pragma unroll
  for(int r = 0; r < 4; ++r){
    int rr  = w * 16 + lk * 4 + r;             // batch row
    int idx = rr * 1024 + col;
    float f  = sigf(aF[r]);
    float gg = tanhf(aG[r]);
    float ii = sigf(sigf(aI[r]));              // faithful double-sigmoid quirk
    float oo = sigf(aO[r]);
    float cn = cs[idx] * f + gg * ii;
    float hn = oo * tanhf(cn);
    cs[idx] = cn;
    hs[idx] = hn;
    hdst[idx] = f2bf(hn);
    if(layer == 1) outs[(size_t)t * 32768 + idx] = hn;
  }
}

// ---- copy final h/c states to d_out tail ----
__global__ void k_final(const float* __restrict__ h_state, const float* __restrict__ c_state,
                        float* __restrict__ tail){
  int i = blockIdx.x * blockDim.x + threadIdx.x;  // 131,072 threads
  if(i < 65536) tail[i] = h_state[i];
  else          tail[i] = c_state[i - 65536];
}

extern "C" void kernel_launch(void* const* d_in, const int* in_sizes, int n_in,
                              void* d_out, int out_size, void* d_ws, size_t ws_size,
                              hipStream_t stream)
{
  (void)in_sizes; (void)n_in; (void)out_size; (void)ws_size;
  const float* x  = (const float*)d_in[0];
  const float* h0 = (const float*)d_in[1];
  const float* c0 = (const float*)d_in[2];
  const float* W  = (const float*)d_in[3];
  const float* b  = (const float*)d_in[4];
  float* out = (float*)d_out;

  char* ws = (char*)d_ws;
  // ws layout (bytes):
  u16x8*          xbf_v   = (u16x8*)(ws);                          //  0        : 32 MB  x bf16
  u16x8*          wpack   = (u16x8*)(ws + 33554432);               // 32 MB     : 32 MB  packed W
  unsigned short* h1x     = (unsigned short*)(ws + 67108864);      // 64 MB     : 513*64KB h1 history
  unsigned short* h2bf    = (unsigned short*)(ws + 100728832);     //           : 128 KB h2 dbuf
  float*          c_state = (float*)(ws + 100859904);              //           : 256 KB
  float*          h_state = (float*)(ws + 101122048);              //           : 256 KB
  // total ~101.4 MB

  k_conv_x<<<8192, 256, 0, stream>>>(x, xbf_v);
  k_pack_w<<<8192, 256, 0, stream>>>(W, wpack);
  k_init<<<256, 256, 0, stream>>>(h0, c0, h1x, h2bf, c_state, h_state);

  const unsigned short* xbf = (const unsigned short*)xbf_v;
  const bf16x8* wpk = (const bf16x8*)wpack;
  for(int p = 0; p <= 512; ++p){
    lstm_step<<<128, 128, 0, stream>>>(xbf, wpk, b, h1x, h2bf, c_state, h_state, out, p);
  }
  k_final<<<512, 256, 0, stream>>>(h_state, c_state, out + 16777216);
}